// Round 10
// baseline (122.125 us; speedup 1.0000x reference)
//
#include <hip/hip_runtime.h>
#include <hip/hip_fp16.h>

typedef _Float16 half8 __attribute__((ext_vector_type(8)));
typedef _Float16 half4v __attribute__((ext_vector_type(4)));
typedef float    floatx4 __attribute__((ext_vector_type(4)));

#define MFMA16(a, b, c) __builtin_amdgcn_mfma_f32_16x16x32_f16((a), (b), (c), 0, 0, 0)

constexpr int T_ = 2048;
constexpr int D_ = 1024;
constexpr int NB = 4;
constexpr int NTILE = 136;             // lower-tri 128x128 tiles per batch
constexpr size_t TILE_ELEMS = 16384;   // 128*128

__device__ __forceinline__ half8 cvt8(floatx4 a, floatx4 b) {
  half8 h;
  h[0] = (_Float16)a[0]; h[1] = (_Float16)a[1]; h[2] = (_Float16)a[2]; h[3] = (_Float16)a[3];
  h[4] = (_Float16)b[0]; h[5] = (_Float16)b[1]; h[6] = (_Float16)b[2]; h[7] = (_Float16)b[3];
  return h;
}

__device__ __forceinline__ void gl16(const void* g, void* l) {
  __builtin_amdgcn_global_load_lds(
      (const __attribute__((address_space(1))) void*)g,
      (__attribute__((address_space(3))) void*)l, 16, 0, 0);
}

// ---- prep 1: Q f32 -> f16 straight cast (linear) ----
__global__ __launch_bounds__(256) void cast_q(const float* __restrict__ Q,
                                              _Float16* __restrict__ Qh) {
  const size_t i = ((size_t)blockIdx.x * 256 + threadIdx.x) * 8;
  *(half8*)(Qh + i) = cvt8(*(const floatx4*)(Q + i), *(const floatx4*)(Q + i + 4));
}

// ---- prep 2: VhT[b][d][t] f16 plain transpose ----
__global__ __launch_bounds__(256) void build_vt(const float* __restrict__ V,
                                                _Float16* __restrict__ VhT) {
  __shared__ _Float16 tile[64][65];
  const int bid = blockIdx.x;
  const int b = bid & 3, tt = (bid >> 2) & 31, dd = bid >> 7;
  const float* Vb = V + ((size_t)b * T_ + tt * 64) * D_ + dd * 64;
#pragma unroll
  for (int k = 0; k < 16; ++k) {
    const int e = k * 256 + threadIdx.x, r = e >> 6, c = e & 63;
    tile[r][c] = (_Float16)Vb[(size_t)r * D_ + c];
  }
  __syncthreads();
#pragma unroll
  for (int k = 0; k < 16; ++k) {
    const int e = k * 256 + threadIdx.x, dr = e >> 6, tc = e & 63;
    VhT[((size_t)b * D_ + dd * 64 + dr) * T_ + tt * 64 + tc] = tile[tc][dr];
  }
}

// ---- S-GEMM: S = Q*V^T (NT), 128^2 tile, BK=32, 3-buf counted-vmcnt pipe ----
__global__ __launch_bounds__(256, 2) void sgemm(const _Float16* __restrict__ Qh,
                                                const float* __restrict__ V,
                                                float* __restrict__ Sp) {
  __shared__ __align__(16) char lds[73728];   // 3 x [ A 8K f16 | B 16K f32 ]
  const int tid = threadIdx.x;
  const int w = tid >> 6, l = tid & 63, l15 = l & 15, hi = l >> 4;
  const int wr = (w >> 1) * 64, wc = (w & 1) * 64;
  const int l2 = l >> 2, l3 = l >> 3;

  const int b = (int)(blockIdx.x & 3);
  int rem = (int)(blockIdx.x >> 2), j = 0;      // j-major (B-panel L2 reuse)
  while (rem >= 16 - j) { rem -= 16 - j; ++j; }
  const int i = j + rem;

  const _Float16* Qb = Qh + ((size_t)(b * T_ + i * 128)) * D_;
  const float*    Vb = V  + ((size_t)(b * T_ + j * 128)) * D_;

  auto STAGE = [&](const int s, const int buf) {
    char* Ad = lds + buf * 24576 + w * 2048;
    char* Bd = lds + buf * 24576 + 8192 + w * 4096;
#pragma unroll
    for (int q = 0; q < 2; ++q) {               // A: 128 rows x 32 k f16
      const int ar = w * 32 + q * 16 + l2;
      const int sw = (ar + (ar >> 2)) & 3;
      gl16(Qb + (size_t)ar * D_ + s * 32 + (((l & 3) ^ sw) << 3), Ad + q * 1024);
    }
#pragma unroll
    for (int q = 0; q < 4; ++q) {               // B: 128 rows x 32 k f32
      const int br = w * 32 + q * 8 + l3;
      gl16(Vb + (size_t)br * D_ + s * 32 + (((l & 7) ^ (br & 7)) << 2), Bd + q * 1024);
    }
  };

  floatx4 acc[4][4];
#pragma unroll
  for (int mi = 0; mi < 4; ++mi)
#pragma unroll
    for (int ni = 0; ni < 4; ++ni) acc[mi][ni] = (floatx4){0.f, 0.f, 0.f, 0.f};

  STAGE(0, 0);
  STAGE(1, 1);
  int bc = 0, bp = 2;                           // compute buf, prefetch buf
  for (int s = 0; s < 32; ++s) {
    if (s < 31) { asm volatile("s_waitcnt vmcnt(6)" ::: "memory"); }  // never 0 mid-loop
    else        { asm volatile("s_waitcnt vmcnt(0)" ::: "memory"); }
    __builtin_amdgcn_s_barrier();
    __builtin_amdgcn_sched_barrier(0);
    if (s + 2 < 32) STAGE(s + 2, bp);           // into buf (s+2)%3; in flight 2 steps
    const char* Ab = lds + bc * 24576;
    const char* Bb = lds + bc * 24576 + 8192;
    half8 af[4], bb[4];
#pragma unroll
    for (int mi = 0; mi < 4; ++mi) {
      const int row = wr + mi * 16 + l15;
      const int sw = (row + (row >> 2)) & 3;
      af[mi] = *(const half8*)(Ab + row * 64 + ((hi ^ sw) << 4));
    }
#pragma unroll
    for (int ni = 0; ni < 4; ++ni) {
      const int row = wc + ni * 16 + l15;
      const int p0 = (hi << 1) ^ (row & 7);
      const floatx4 f0 = *(const floatx4*)(Bb + row * 128 + (p0 << 4));
      const floatx4 f1 = *(const floatx4*)(Bb + row * 128 + ((p0 ^ 1) << 4));
      bb[ni] = cvt8(f0, f1);
    }
#pragma unroll
    for (int mi = 0; mi < 4; ++mi)
#pragma unroll
      for (int ni = 0; ni < 4; ++ni)
        acc[mi][ni] = MFMA16(af[mi], bb[ni], acc[mi][ni]);
    bc = (bc == 2) ? 0 : bc + 1;
    bp = (bp == 2) ? 0 : bp + 1;
  }

  float* tp = Sp + (size_t)(b * NTILE + ((i * (i + 1)) >> 1) + j) * TILE_ELEMS;
#pragma unroll
  for (int mi = 0; mi < 4; ++mi)
#pragma unroll
    for (int r = 0; r < 4; ++r) {
      const int row = wr + mi * 16 + 4 * hi + r;
#pragma unroll
      for (int ni = 0; ni < 4; ++ni)
        tp[row * 128 + wc + ni * 16 + l15] = acc[mi][ni][r];
    }
}

// ---- softmax: half-wave per row, float4; P f16 in-place (row slot 512B) ----
__global__ __launch_bounds__(256) void smax(float* __restrict__ Sp,
                                            float* __restrict__ lrow) {
  const int b = (int)(blockIdx.x & 3), t = (int)(blockIdx.x >> 2);
  const int wv = threadIdx.x >> 6, l = threadIdx.x & 63;
  const int l32 = l & 31;
  const int row = 2040 - t * 8 + wv * 2 + (l >> 5);   // LPT: long rows first
  const int i = row >> 7, r = row & 127;
  char* tb0 = (char*)(Sp + (size_t)(b * NTILE + ((i * (i + 1)) >> 1)) * TILE_ELEMS);

  float mx = -1e30f;
  for (int j = 0; j <= i; ++j) {
    const floatx4 v = *(const floatx4*)(tb0 + (size_t)j * 65536 + r * 512 + l32 * 16);
    const int col0 = j * 128 + l32 * 4;
#pragma unroll
    for (int e = 0; e < 4; ++e)
      if (col0 + e <= row) mx = fmaxf(mx, v[e]);
  }
#pragma unroll
  for (int off = 1; off < 32; off <<= 1) mx = fmaxf(mx, __shfl_xor(mx, off));

  float sum = 0.f;
  for (int j = 0; j <= i; ++j) {
    char* tbj = tb0 + (size_t)j * 65536;
    const floatx4 v = *(const floatx4*)(tbj + r * 512 + l32 * 16);
    const int col0 = j * 128 + l32 * 4;
    half4v hv;
#pragma unroll
    for (int e = 0; e < 4; ++e) {
      const float p = (col0 + e <= row) ? __expf(v[e] - mx) : 0.f;
      sum += p;
      hv[e] = (_Float16)p;
    }
    *(half4v*)(tbj + r * 512 + l32 * 8) = hv;   // own row slot only
  }
#pragma unroll
  for (int off = 1; off < 32; off <<= 1) sum += __shfl_xor(sum, off);
  if (l32 == 0) lrow[b * 2048 + row] = sum;
}

// ---- PV: O = P*V (via VhT), 128^2 tile, BK=32, 3-buf counted-vmcnt pipe ----
__global__ __launch_bounds__(256, 3) void pv(const float* __restrict__ Sp,
                                             const _Float16* __restrict__ VhT,
                                             const float* __restrict__ lrow,
                                             float* __restrict__ O) {
  __shared__ __align__(16) char lds[49152];   // 3 x [ A 8K | B 8K ] f16
  __shared__ float Lsh[128];
  const int tid = threadIdx.x;
  const int w = tid >> 6, l = tid & 63, l15 = l & 15, hi = l >> 4;
  const int wr = (w >> 1) * 64, wc = (w & 1) * 64;
  const int l2 = l >> 2;

  const int b = (int)(blockIdx.x & 3), t = (int)(blockIdx.x >> 2);
  const int r_ = t >> 3;
  const int i = (r_ < 8) ? (15 - r_) : (r_ - 8);   // co-resident pair balance
  const int nc = t & 7;
  const int ns = (i + 1) * 4;

  const char* Pbase = (const char*)(Sp + (size_t)(b * NTILE + ((i * (i + 1)) >> 1)) * TILE_ELEMS);
  const _Float16* Vt = VhT + ((size_t)(b * D_ + nc * 128)) * T_;
  if (tid < 128) Lsh[tid] = lrow[b * 2048 + i * 128 + tid];

  auto STAGE = [&](const int s, const int buf) {
    char* Ad = lds + buf * 16384 + w * 2048;
    char* Bd = lds + buf * 16384 + 8192 + w * 2048;
#pragma unroll
    for (int q = 0; q < 2; ++q) {
      const int ar = w * 32 + q * 16 + l2;
      const int sw = (ar + (ar >> 2)) & 3;
      gl16(Pbase + (size_t)(s >> 2) * 65536 + ar * 512 + (s & 3) * 64 +
               (((l & 3) ^ sw) << 4),
           Ad + q * 1024);
      gl16(Vt + (size_t)ar * T_ + s * 32 + (((l & 3) ^ sw) << 3), Bd + q * 1024);
    }
  };

  floatx4 acc[4][4];
#pragma unroll
  for (int mi = 0; mi < 4; ++mi)
#pragma unroll
    for (int ni = 0; ni < 4; ++ni) acc[mi][ni] = (floatx4){0.f, 0.f, 0.f, 0.f};

  STAGE(0, 0);
  STAGE(1, 1);
  int bc = 0, bp = 2;
  for (int s = 0; s < ns; ++s) {
    if (s < ns - 1) { asm volatile("s_waitcnt vmcnt(4)" ::: "memory"); }
    else            { asm volatile("s_waitcnt vmcnt(0)" ::: "memory"); }
    __builtin_amdgcn_s_barrier();
    __builtin_amdgcn_sched_barrier(0);
    if (s + 2 < ns) STAGE(s + 2, bp);
    const char* Ab = lds + bc * 16384;
    const char* Bb = lds + bc * 16384 + 8192;
    half8 af[4], bb[4];
#pragma unroll
    for (int mi = 0; mi < 4; ++mi) {
      const int row = wr + mi * 16 + l15;
      const int sw = (row + (row >> 2)) & 3;
      af[mi] = *(const half8*)(Ab + row * 64 + ((hi ^ sw) << 4));
    }
#pragma unroll
    for (int ni = 0; ni < 4; ++ni) {
      const int row = wc + ni * 16 + l15;
      const int sw = (row + (row >> 2)) & 3;
      bb[ni] = *(const half8*)(Bb + row * 64 + ((hi ^ sw) << 4));
    }
#pragma unroll
    for (int mi = 0; mi < 4; ++mi)
#pragma unroll
      for (int ni = 0; ni < 4; ++ni)
        acc[mi][ni] = MFMA16(af[mi], bb[ni], acc[mi][ni]);
    bc = (bc == 2) ? 0 : bc + 1;
    bp = (bp == 2) ? 0 : bp + 1;
  }

  float* Ob = O + ((size_t)b * T_ + i * 128) * D_ + nc * 128;
#pragma unroll
  for (int mi = 0; mi < 4; ++mi)
#pragma unroll
    for (int r = 0; r < 4; ++r) {
      const int rl = wr + mi * 16 + 4 * hi + r;
      const float inv = 1.0f / Lsh[rl];
#pragma unroll
      for (int ni = 0; ni < 4; ++ni)
        Ob[(size_t)rl * D_ + wc + ni * 16 + l15] = acc[mi][ni][r] * inv;
    }
}

// ---- fallback (ws too small — slow but correct) ----
__global__ __launch_bounds__(256) void attn_fb(const float* __restrict__ Q,
                                               const float* __restrict__ V,
                                               float* __restrict__ O) {
  __shared__ float sc[2048];
  __shared__ float red[4];
  const int b = (int)(blockIdx.x >> 11), m = (int)(blockIdx.x & 2047);
  const int tid = threadIdx.x;
  const float* Qr = Q + ((size_t)b * T_ + m) * D_;
  for (int kv = tid; kv <= m; kv += 256) {
    const float* Vr = V + ((size_t)b * T_ + kv) * D_;
    float s = 0.f;
    for (int d = 0; d < D_; d += 4) {
      floatx4 q4 = *(const floatx4*)(Qr + d), v4 = *(const floatx4*)(Vr + d);
      s += q4[0] * v4[0] + q4[1] * v4[1] + q4[2] * v4[2] + q4[3] * v4[3];
    }
    sc[kv] = s;
  }
  __syncthreads();
  float mx = -1e30f;
  for (int kv = tid; kv <= m; kv += 256) mx = fmaxf(mx, sc[kv]);
#pragma unroll
  for (int off = 1; off < 64; off <<= 1) mx = fmaxf(mx, __shfl_xor(mx, off));
  if ((tid & 63) == 0) red[tid >> 6] = mx;
  __syncthreads();
  mx = fmaxf(fmaxf(red[0], red[1]), fmaxf(red[2], red[3]));
  __syncthreads();
  float sum = 0.f;
  for (int kv = tid; kv <= m; kv += 256) { float p = __expf(sc[kv] - mx); sc[kv] = p; sum += p; }
#pragma unroll
  for (int off = 1; off < 64; off <<= 1) sum += __shfl_xor(sum, off);
  __syncthreads();
  if ((tid & 63) == 0) red[tid >> 6] = sum;
  __syncthreads();
  const float inv = 1.0f / (red[0] + red[1] + red[2] + red[3]);
  float* Or = O + ((size_t)b * T_ + m) * D_;
  const int d = tid * 4;
  floatx4 o = {0.f, 0.f, 0.f, 0.f};
  for (int kv = 0; kv <= m; ++kv) {
    const float p = sc[kv];
    const floatx4 v4 = *(const floatx4*)(V + ((size_t)b * T_ + kv) * D_ + d);
    o[0] += p * v4[0]; o[1] += p * v4[1]; o[2] += p * v4[2]; o[3] += p * v4[3];
  }
  o[0] *= inv; o[1] *= inv; o[2] *= inv; o[3] *= inv;
  *(floatx4*)(Or + d) = o;
}

extern "C" void kernel_launch(void* const* d_in, const int* in_sizes, int n_in,
                              void* d_out, int out_size, void* d_ws, size_t ws_size,
                              hipStream_t stream) {
  const float* q = (const float*)d_in[0];
  const float* v = (const float*)d_in[1];
  float* out = (float*)d_out;

  const size_t OFF_S = 16777216;                                    // Qh/VhT slot (reused)
  const size_t OFF_L = OFF_S + (size_t)NB * NTILE * TILE_ELEMS * 4; // 52,428,800
  const size_t NEED = OFF_L + (size_t)NB * 2048 * 4;                // ~52.5 MB

  if (ws_size >= NEED) {
    _Float16* fh = (_Float16*)d_ws;                 // Qh, later VhT
    float* Sp = (float*)((char*)d_ws + OFF_S);
    float* lr = (float*)((char*)d_ws + OFF_L);
    cast_q<<<dim3(4096), dim3(256), 0, stream>>>(q, fh);
    sgemm<<<dim3(NB * NTILE), dim3(256), 0, stream>>>(fh, v, Sp);
    smax<<<dim3(1024), dim3(256), 0, stream>>>(Sp, lr);
    build_vt<<<dim3(2048), dim3(256), 0, stream>>>(v, fh);   // Qh dead -> VhT
    pv<<<dim3(512), dim3(256), 0, stream>>>(Sp, fh, lr, out);
  } else {
    attn_fb<<<dim3(NB * T_), dim3(256), 0, stream>>>(q, v, out);
  }
}

// Round 11
// 121.977 us; speedup vs baseline: 1.0012x; 1.0012x over previous
//
#include <hip/hip_runtime.h>
#include <hip/hip_fp16.h>

typedef _Float16 half8 __attribute__((ext_vector_type(8)));
typedef _Float16 half4v __attribute__((ext_vector_type(4)));
typedef float    floatx4 __attribute__((ext_vector_type(4)));

#define MFMA16(a, b, c) __builtin_amdgcn_mfma_f32_16x16x32_f16((a), (b), (c), 0, 0, 0)

constexpr int T_ = 2048;
constexpr int D_ = 1024;
constexpr int NB = 4;
constexpr int NTILE = 136;             // lower-tri 128x128 tiles per batch
constexpr size_t TILE_ELEMS = 16384;   // 128*128

__device__ __forceinline__ half8 cvt8(floatx4 a, floatx4 b) {
  half8 h;
  h[0] = (_Float16)a[0]; h[1] = (_Float16)a[1]; h[2] = (_Float16)a[2]; h[3] = (_Float16)a[3];
  h[4] = (_Float16)b[0]; h[5] = (_Float16)b[1]; h[6] = (_Float16)b[2]; h[7] = (_Float16)b[3];
  return h;
}

__device__ __forceinline__ void gl16(const void* g, void* l) {
  __builtin_amdgcn_global_load_lds(
      (const __attribute__((address_space(1))) void*)g,
      (__attribute__((address_space(3))) void*)l, 16, 0, 0);
}

// ---- prep 1: Q f32 -> f16 straight cast (linear) ----
__global__ __launch_bounds__(256) void cast_q(const float* __restrict__ Q,
                                              _Float16* __restrict__ Qh) {
  const size_t i = ((size_t)blockIdx.x * 256 + threadIdx.x) * 8;
  *(half8*)(Qh + i) = cvt8(*(const floatx4*)(Q + i), *(const floatx4*)(Q + i + 4));
}

// ---- prep 2: VhT[b][d][t] f16 plain transpose ----
__global__ __launch_bounds__(256) void build_vt(const float* __restrict__ V,
                                                _Float16* __restrict__ VhT) {
  __shared__ _Float16 tile[64][65];
  const int bid = blockIdx.x;
  const int b = bid & 3, tt = (bid >> 2) & 31, dd = bid >> 7;
  const float* Vb = V + ((size_t)b * T_ + tt * 64) * D_ + dd * 64;
#pragma unroll
  for (int k = 0; k < 16; ++k) {
    const int e = k * 256 + threadIdx.x, r = e >> 6, c = e & 63;
    tile[r][c] = (_Float16)Vb[(size_t)r * D_ + c];
  }
  __syncthreads();
#pragma unroll
  for (int k = 0; k < 16; ++k) {
    const int e = k * 256 + threadIdx.x, dr = e >> 6, tc = e & 63;
    VhT[((size_t)b * D_ + dd * 64 + dr) * T_ + tt * 64 + tc] = tile[tc][dr];
  }
}

// ---- S-GEMM: S = Q*V^T (NT), 64x128 tile, BK=32, single-buf, 1088 blocks ----
__global__ __launch_bounds__(256, 4) void sgemm(const _Float16* __restrict__ Qh,
                                                const float* __restrict__ V,
                                                float* __restrict__ Sp) {
  __shared__ __align__(16) char As[4096];    // 64 q-rows x 32 k f16
  __shared__ __align__(16) char Bs[16384];   // 128 kv-rows x 32 k f32
  const int tid = threadIdx.x;
  const int w = tid >> 6, l = tid & 63, l15 = l & 15, hi = l >> 4;
  const int wr = (w >> 1) * 32, wc = (w & 1) * 64;

  const int b = (int)(blockIdx.x & 3);
  int rem = (int)(blockIdx.x >> 2), j = 0;       // j-major (B-panel L2 reuse)
  while (rem >= 32 - 2 * j) { rem -= 32 - 2 * j; ++j; }
  const int i64 = 2 * j + rem;                   // 64-row Q block
  const int I = i64 >> 1;

  const _Float16* Qb = Qh + ((size_t)(b * T_ + i64 * 64)) * D_;
  const float*    Vb = V  + ((size_t)(b * T_ + j * 128)) * D_;

  // staging constants
  const int arow = w * 16 + (l >> 2);            // A: 1 gl16/thread
  const int aoff = ((((arow + (arow >> 2)) & 3) ^ (l & 3)) << 3);
  const int brow0 = w * 32 + (l >> 3);           // B: 4 gl16/thread
  const int boff = (((l & 7) ^ (l >> 3)) << 2);
  char* Adst = As + w * 1024;
  char* Bdst = Bs + w * 4096;

  floatx4 acc[2][4];
#pragma unroll
  for (int mi = 0; mi < 2; ++mi)
#pragma unroll
    for (int ni = 0; ni < 4; ++ni) acc[mi][ni] = (floatx4){0.f, 0.f, 0.f, 0.f};

  for (int s = 0; s < 32; ++s) {
    gl16(Qb + (size_t)arow * D_ + s * 32 + aoff, Adst);
#pragma unroll
    for (int q = 0; q < 4; ++q)
      gl16(Vb + (size_t)(brow0 + q * 8) * D_ + s * 32 + boff, Bdst + q * 1024);
    __syncthreads();                             // vmcnt drain -> tile ready
    half8 af[2], bb[4];
#pragma unroll
    for (int mi = 0; mi < 2; ++mi) {
      const int row = wr + mi * 16 + l15;
      const int sw = (row + (row >> 2)) & 3;
      af[mi] = *(const half8*)(As + row * 64 + ((hi ^ sw) << 4));
    }
#pragma unroll
    for (int ni = 0; ni < 4; ++ni) {
      const int row = wc + ni * 16 + l15;
      const int p0 = (hi << 1) ^ (row & 7);
      const floatx4 f0 = *(const floatx4*)(Bs + row * 128 + (p0 << 4));
      const floatx4 f1 = *(const floatx4*)(Bs + row * 128 + ((p0 ^ 1) << 4));
      bb[ni] = cvt8(f0, f1);
    }
#pragma unroll
    for (int mi = 0; mi < 2; ++mi)
#pragma unroll
      for (int ni = 0; ni < 4; ++ni)
        acc[mi][ni] = MFMA16(af[mi], bb[ni], acc[mi][ni]);
    __syncthreads();                             // reads done before next stage
  }

  float* tp = Sp + (size_t)(b * NTILE + ((I * (I + 1)) >> 1) + j) * TILE_ELEMS +
              (i64 & 1) * 8192;
#pragma unroll
  for (int mi = 0; mi < 2; ++mi)
#pragma unroll
    for (int r = 0; r < 4; ++r) {
      const int row = wr + mi * 16 + 4 * hi + r;
#pragma unroll
      for (int ni = 0; ni < 4; ++ni)
        tp[row * 128 + wc + ni * 16 + l15] = acc[mi][ni][r];
    }
}

// ---- softmax: half-wave per row, float4; P f16 in-place (row slot 512B) ----
__global__ __launch_bounds__(256) void smax(float* __restrict__ Sp,
                                            float* __restrict__ lrow) {
  const int b = (int)(blockIdx.x & 3), t = (int)(blockIdx.x >> 2);
  const int wv = threadIdx.x >> 6, l = threadIdx.x & 63;
  const int l32 = l & 31;
  const int row = 2040 - t * 8 + wv * 2 + (l >> 5);   // LPT: long rows first
  const int i = row >> 7, r = row & 127;
  char* tb0 = (char*)(Sp + (size_t)(b * NTILE + ((i * (i + 1)) >> 1)) * TILE_ELEMS);

  float mx = -1e30f;
  for (int j = 0; j <= i; ++j) {
    const floatx4 v = *(const floatx4*)(tb0 + (size_t)j * 65536 + r * 512 + l32 * 16);
    const int col0 = j * 128 + l32 * 4;
#pragma unroll
    for (int e = 0; e < 4; ++e)
      if (col0 + e <= row) mx = fmaxf(mx, v[e]);
  }
#pragma unroll
  for (int off = 1; off < 32; off <<= 1) mx = fmaxf(mx, __shfl_xor(mx, off));

  float sum = 0.f;
  for (int j = 0; j <= i; ++j) {
    char* tbj = tb0 + (size_t)j * 65536;
    const floatx4 v = *(const floatx4*)(tbj + r * 512 + l32 * 16);
    const int col0 = j * 128 + l32 * 4;
    half4v hv;
#pragma unroll
    for (int e = 0; e < 4; ++e) {
      const float p = (col0 + e <= row) ? __expf(v[e] - mx) : 0.f;
      sum += p;
      hv[e] = (_Float16)p;
    }
    *(half4v*)(tbj + r * 512 + l32 * 8) = hv;   // own row slot only
  }
#pragma unroll
  for (int off = 1; off < 32; off <<= 1) sum += __shfl_xor(sum, off);
  if (l32 == 0) lrow[b * 2048 + row] = sum;
}

// ---- PV: O = P*V (via VhT), 128x64 tile, BK=32, single-buf, 1024 blocks ----
__global__ __launch_bounds__(256, 4) void pv(const float* __restrict__ Sp,
                                             const _Float16* __restrict__ VhT,
                                             const float* __restrict__ lrow,
                                             float* __restrict__ O) {
  __shared__ __align__(16) char As[8192];    // P 128 q-rows x 32 kv f16
  __shared__ __align__(16) char Bs[4096];    // VhT 64 d-rows x 32 kv f16
  __shared__ float Lsh[128];
  const int tid = threadIdx.x;
  const int w = tid >> 6, l = tid & 63, l15 = l & 15, hi = l >> 4;
  const int wr = w * 32;

  const int b = (int)(blockIdx.x & 3);
  const int u = (int)(blockIdx.x >> 2);            // 0..255
  const int iidx = (u + (u >> 4)) & 15;            // mixes i across CU residency
  const int i = (iidx < 8) ? (15 - iidx) : (iidx - 8);
  const int nc = u >> 4;                           // 0..15, 64-wide D slice
  const int ns = (i + 1) * 4;

  const char* Pbase = (const char*)(Sp + (size_t)(b * NTILE + ((i * (i + 1)) >> 1)) * TILE_ELEMS);
  const _Float16* Vt = VhT + ((size_t)(b * D_ + nc * 64)) * T_;
  if (tid < 128) Lsh[tid] = lrow[b * 2048 + i * 128 + tid];

  // staging constants
  const int vrow = w * 16 + (l >> 2);              // B: 1 gl16/thread
  const int voff = ((((vrow + (vrow >> 2)) & 3) ^ (l & 3)) << 3);
  char* Adst = As + w * 2048;
  char* Bdst = Bs + w * 1024;

  floatx4 acc[2][4];
#pragma unroll
  for (int mi = 0; mi < 2; ++mi)
#pragma unroll
    for (int ni = 0; ni < 4; ++ni) acc[mi][ni] = (floatx4){0.f, 0.f, 0.f, 0.f};

  for (int s = 0; s < ns; ++s) {
#pragma unroll
    for (int q = 0; q < 2; ++q) {                  // A: 2 gl16/thread
      const int ar = w * 32 + q * 16 + (l >> 2);
      const int sw = (((ar + (ar >> 2)) & 3) ^ (l & 3)) << 4;
      gl16(Pbase + (size_t)(s >> 2) * 65536 + ar * 512 + (s & 3) * 64 + sw,
           Adst + q * 1024);
    }
    gl16(Vt + (size_t)vrow * T_ + s * 32 + voff, Bdst);
    __syncthreads();
    half8 af[2], bb[4];
#pragma unroll
    for (int mi = 0; mi < 2; ++mi) {
      const int row = wr + mi * 16 + l15;
      const int sw = (row + (row >> 2)) & 3;
      af[mi] = *(const half8*)(As + row * 64 + ((hi ^ sw) << 4));
    }
#pragma unroll
    for (int ni = 0; ni < 4; ++ni) {
      const int row = ni * 16 + l15;
      const int sw = (row + (row >> 2)) & 3;
      bb[ni] = *(const half8*)(Bs + row * 64 + ((hi ^ sw) << 4));
    }
#pragma unroll
    for (int mi = 0; mi < 2; ++mi)
#pragma unroll
      for (int ni = 0; ni < 4; ++ni)
        acc[mi][ni] = MFMA16(af[mi], bb[ni], acc[mi][ni]);
    __syncthreads();
  }

  float* Ob = O + ((size_t)b * T_ + i * 128) * D_ + nc * 64;
#pragma unroll
  for (int mi = 0; mi < 2; ++mi)
#pragma unroll
    for (int r = 0; r < 4; ++r) {
      const int rl = wr + mi * 16 + 4 * hi + r;
      const float inv = 1.0f / Lsh[rl];
#pragma unroll
      for (int ni = 0; ni < 4; ++ni)
        Ob[(size_t)rl * D_ + ni * 16 + l15] = acc[mi][ni][r] * inv;
    }
}

// ---- fallback (ws too small — slow but correct) ----
__global__ __launch_bounds__(256) void attn_fb(const float* __restrict__ Q,
                                               const float* __restrict__ V,
                                               float* __restrict__ O) {
  __shared__ float sc[2048];
  __shared__ float red[4];
  const int b = (int)(blockIdx.x >> 11), m = (int)(blockIdx.x & 2047);
  const int tid = threadIdx.x;
  const float* Qr = Q + ((size_t)b * T_ + m) * D_;
  for (int kv = tid; kv <= m; kv += 256) {
    const float* Vr = V + ((size_t)b * T_ + kv) * D_;
    float s = 0.f;
    for (int d = 0; d < D_; d += 4) {
      floatx4 q4 = *(const floatx4*)(Qr + d), v4 = *(const floatx4*)(Vr + d);
      s += q4[0] * v4[0] + q4[1] * v4[1] + q4[2] * v4[2] + q4[3] * v4[3];
    }
    sc[kv] = s;
  }
  __syncthreads();
  float mx = -1e30f;
  for (int kv = tid; kv <= m; kv += 256) mx = fmaxf(mx, sc[kv]);
#pragma unroll
  for (int off = 1; off < 64; off <<= 1) mx = fmaxf(mx, __shfl_xor(mx, off));
  if ((tid & 63) == 0) red[tid >> 6] = mx;
  __syncthreads();
  mx = fmaxf(fmaxf(red[0], red[1]), fmaxf(red[2], red[3]));
  __syncthreads();
  float sum = 0.f;
  for (int kv = tid; kv <= m; kv += 256) { float p = __expf(sc[kv] - mx); sc[kv] = p; sum += p; }
#pragma unroll
  for (int off = 1; off < 64; off <<= 1) sum += __shfl_xor(sum, off);
  __syncthreads();
  if ((tid & 63) == 0) red[tid >> 6] = sum;
  __syncthreads();
  const float inv = 1.0f / (red[0] + red[1] + red[2] + red[3]);
  float* Or = O + ((size_t)b * T_ + m) * D_;
  const int d = tid * 4;
  floatx4 o = {0.f, 0.f, 0.f, 0.f};
  for (int kv = 0; kv <= m; ++kv) {
    const float p = sc[kv];
    const floatx4 v4 = *(const floatx4*)(V + ((size_t)b * T_ + kv) * D_ + d);
    o[0] += p * v4[0]; o[1] += p * v4[1]; o[2] += p * v4[2]; o[3] += p * v4[3];
  }
  o[0] *= inv; o[1] *= inv; o[2] *= inv; o[3] *= inv;
  *(floatx4*)(Or + d) = o;
}

extern "C" void kernel_launch(void* const* d_in, const int* in_sizes, int n_in,
                              void* d_out, int out_size, void* d_ws, size_t ws_size,
                              hipStream_t stream) {
  const float* q = (const float*)d_in[0];
  const float* v = (const float*)d_in[1];
  float* out = (float*)d_out;

  const size_t OFF_S = 16777216;                                    // Qh/VhT slot (reused)
  const size_t OFF_L = OFF_S + (size_t)NB * NTILE * TILE_ELEMS * 4; // 52,428,800
  const size_t NEED = OFF_L + (size_t)NB * 2048 * 4;                // ~52.5 MB

  if (ws_size >= NEED) {
    _Float16* fh = (_Float16*)d_ws;                 // Qh, later VhT
    float* Sp = (float*)((char*)d_ws + OFF_S);
    float* lr = (float*)((char*)d_ws + OFF_L);
    cast_q<<<dim3(4096), dim3(256), 0, stream>>>(q, fh);
    sgemm<<<dim3(NB * 272), dim3(256), 0, stream>>>(fh, v, Sp);
    smax<<<dim3(1024), dim3(256), 0, stream>>>(Sp, lr);
    build_vt<<<dim3(2048), dim3(256), 0, stream>>>(v, fh);   // Qh dead -> VhT
    pv<<<dim3(1024), dim3(256), 0, stream>>>(Sp, fh, lr, out);
  } else {
    attn_fb<<<dim3(NB * T_), dim3(256), 0, stream>>>(q, v, out);
  }
}

// Round 12
// 118.183 us; speedup vs baseline: 1.0334x; 1.0321x over previous
//
#include <hip/hip_runtime.h>
#include <hip/hip_fp16.h>

typedef _Float16 half8 __attribute__((ext_vector_type(8)));
typedef float    floatx4 __attribute__((ext_vector_type(4)));
typedef unsigned int uintx4 __attribute__((ext_vector_type(4)));

#define MFMA16(a, b, c) __builtin_amdgcn_mfma_f32_16x16x32_f16((a), (b), (c), 0, 0, 0)

constexpr int T_ = 2048;
constexpr int D_ = 1024;
constexpr int NB = 4;
constexpr int NTILE = 136;               // lower-tri 128x128 tiles per batch
constexpr size_t PT_ELEMS = 16384;       // P tile: 128x128 f16

__device__ __forceinline__ half8 cvt8(floatx4 a, floatx4 b) {
  half8 h;
  h[0] = (_Float16)a[0]; h[1] = (_Float16)a[1]; h[2] = (_Float16)a[2]; h[3] = (_Float16)a[3];
  h[4] = (_Float16)b[0]; h[5] = (_Float16)b[1]; h[6] = (_Float16)b[2]; h[7] = (_Float16)b[3];
  return h;
}

__device__ __forceinline__ void gl16(const void* g, void* l) {
  __builtin_amdgcn_global_load_lds(
      (const __attribute__((address_space(1))) void*)g,
      (__attribute__((address_space(3))) void*)l, 16, 0, 0);
}

// ---- prep: f32 -> f16 straight cast (used for Q and V) ----
__global__ __launch_bounds__(256) void cast_h(const float* __restrict__ X,
                                              _Float16* __restrict__ Xh) {
  const size_t i = ((size_t)blockIdx.x * 256 + threadIdx.x) * 8;
  *(half8*)(Xh + i) = cvt8(*(const floatx4*)(X + i), *(const floatx4*)(X + i + 4));
}

// ---- prep: VhT[b][d][t] f16 plain transpose ----
__global__ __launch_bounds__(256) void build_vt(const float* __restrict__ V,
                                                _Float16* __restrict__ VhT) {
  __shared__ _Float16 tile[64][65];
  const int bid = blockIdx.x;
  const int b = bid & 3, tt = (bid >> 2) & 31, dd = bid >> 7;
  const float* Vb = V + ((size_t)b * T_ + tt * 64) * D_ + dd * 64;
#pragma unroll
  for (int k = 0; k < 16; ++k) {
    const int e = k * 256 + threadIdx.x, r = e >> 6, c = e & 63;
    tile[r][c] = (_Float16)Vb[(size_t)r * D_ + c];
  }
  __syncthreads();
#pragma unroll
  for (int k = 0; k < 16; ++k) {
    const int e = k * 256 + threadIdx.x, dr = e >> 6, tc = e & 63;
    VhT[((size_t)b * D_ + dd * 64 + dr) * T_ + tt * 64 + tc] = tile[tc][dr];
  }
}

// ---- S-GEMM + fused per-tile softmax partials ----
// 128^2 tile, BK=128 (8 steps), f16 A/B, gload_lds; epilogue computes
// per-tile row max m_j, row sum l_j, writes P = exp(s - m_j) as f16 tile.
__global__ __launch_bounds__(256, 2) void sgemm(const _Float16* __restrict__ Qh,
                                                const _Float16* __restrict__ Vh,
                                                _Float16* __restrict__ Pt,
                                                float* __restrict__ mg,
                                                float* __restrict__ lg) {
  extern __shared__ __align__(16) char lds[];   // As 32K | Bs 32K
  char* As = lds;
  char* Bs = lds + 32768;
  const int tid = threadIdx.x;
  const int w = tid >> 6, l = tid & 63, l15 = l & 15, hi = l >> 4;
  const int wr = (w >> 1) * 64, wc = (w & 1) * 64;

  const int b = (int)(blockIdx.x & 3);
  int rem = (int)(blockIdx.x >> 2), j = 0;      // j-major (B-panel L2 reuse)
  while (rem >= 16 - j) { rem -= 16 - j; ++j; }
  const int i = j + rem;

  const _Float16* Qb = Qh + ((size_t)(b * T_ + i * 128)) * D_;
  const _Float16* Vb = Vh + ((size_t)(b * T_ + j * 128)) * D_;
  const int srow = w * 32 + (l >> 4);           // +q*4 ; lane chunk l&15
  char* Adst = As + w * 8192;
  char* Bdst = Bs + w * 8192;

  floatx4 acc[4][4];
#pragma unroll
  for (int mi = 0; mi < 4; ++mi)
#pragma unroll
    for (int ni = 0; ni < 4; ++ni) acc[mi][ni] = (floatx4){0.f, 0.f, 0.f, 0.f};

  for (int s = 0; s < 8; ++s) {
#pragma unroll
    for (int q = 0; q < 8; ++q) {               // 8+8 gl16: A,B 128 rows x 128k f16
      const int r0 = srow + q * 4;
      const int sc = ((l & 15) ^ (r0 & 15)) * 8;   // src-XOR -> conflict-free read
      gl16(Qb + (size_t)r0 * D_ + s * 128 + sc, Adst + q * 1024);
      gl16(Vb + (size_t)r0 * D_ + s * 128 + sc, Bdst + q * 1024);
    }
    __syncthreads();                            // vmcnt drain -> tile ready
#pragma unroll
    for (int s32 = 0; s32 < 4; ++s32) {
      half8 af[4], bb[4];
#pragma unroll
      for (int mi = 0; mi < 4; ++mi) {
        const int row = wr + mi * 16 + l15;
        af[mi] = *(const half8*)(As + row * 256 + (((s32 * 4 + hi) ^ (row & 15)) << 4));
      }
#pragma unroll
      for (int ni = 0; ni < 4; ++ni) {
        const int row = wc + ni * 16 + l15;
        bb[ni] = *(const half8*)(Bs + row * 256 + (((s32 * 4 + hi) ^ (row & 15)) << 4));
      }
#pragma unroll
      for (int mi = 0; mi < 4; ++mi)
#pragma unroll
        for (int ni = 0; ni < 4; ++ni)
          acc[mi][ni] = MFMA16(af[mi], bb[ni], acc[mi][ni]);
    }
    __syncthreads();                            // reads done before next stage
  }

  // ---- fused epilogue: mask, row-max, P=exp(s-m), row-sum, stores ----
  float* Mex = (float*)Bs;                      // [2][128]
  float* Lex = (float*)(Bs + 1024);             // [2][128]

  if (i == j) {                                 // causal mask on diagonal tile
#pragma unroll
    for (int mi = 0; mi < 4; ++mi)
#pragma unroll
      for (int ni = 0; ni < 4; ++ni) {
        const int col = wc + ni * 16 + l15;
        const int row0 = wr + mi * 16 + 4 * hi;
#pragma unroll
        for (int r = 0; r < 4; ++r)
          if (col > row0 + r) acc[mi][ni][r] = -1e30f;
      }
  }

  floatx4 mrow[4];
#pragma unroll
  for (int mi = 0; mi < 4; ++mi) {
#pragma unroll
    for (int r = 0; r < 4; ++r)
      mrow[mi][r] = fmaxf(fmaxf(acc[mi][0][r], acc[mi][1][r]),
                          fmaxf(acc[mi][2][r], acc[mi][3][r]));
#pragma unroll
    for (int off = 1; off < 16; off <<= 1)
#pragma unroll
      for (int r = 0; r < 4; ++r)
        mrow[mi][r] = fmaxf(mrow[mi][r], __shfl_xor(mrow[mi][r], off));
  }
  if (l15 == 0) {
#pragma unroll
    for (int mi = 0; mi < 4; ++mi)
      *(floatx4*)&Mex[(w & 1) * 128 + wr + mi * 16 + 4 * hi] = mrow[mi];
  }
  __syncthreads();
#pragma unroll
  for (int mi = 0; mi < 4; ++mi) {
    const floatx4 m0 = *(const floatx4*)&Mex[wr + mi * 16 + 4 * hi];
    const floatx4 m1 = *(const floatx4*)&Mex[128 + wr + mi * 16 + 4 * hi];
#pragma unroll
    for (int r = 0; r < 4; ++r) mrow[mi][r] = fmaxf(m0[r], m1[r]);
  }

  floatx4 lsum[4];
#pragma unroll
  for (int mi = 0; mi < 4; ++mi) {
    lsum[mi] = (floatx4){0.f, 0.f, 0.f, 0.f};
    const int row0 = wr + mi * 16 + 4 * hi;
#pragma unroll
    for (int ni = 0; ni < 4; ++ni) {
      const int col = wc + ni * 16 + l15;
#pragma unroll
      for (int r = 0; r < 4; ++r) {
        const float p = __expf(acc[mi][ni][r] - mrow[mi][r]);
        lsum[mi][r] += p;
        *(_Float16*)(As + (row0 + r) * 256 + col * 2) = (_Float16)p;  // P into LDS
      }
    }
#pragma unroll
    for (int off = 1; off < 16; off <<= 1)
#pragma unroll
      for (int r = 0; r < 4; ++r) lsum[mi][r] += __shfl_xor(lsum[mi][r], off);
  }
  if (l15 == 0) {
#pragma unroll
    for (int mi = 0; mi < 4; ++mi)
      *(floatx4*)&Lex[(w & 1) * 128 + wr + mi * 16 + 4 * hi] = lsum[mi];
  }
  __syncthreads();

  if (((w & 1) == 0) && l15 == 0) {             // m/l sidecar (one writer per row)
    const size_t base = ((size_t)(b * 16 + j)) * 2048 + i * 128;
#pragma unroll
    for (int mi = 0; mi < 4; ++mi) {
      const int r0 = wr + mi * 16 + 4 * hi;
      const floatx4 l0 = *(const floatx4*)&Lex[r0];
      const floatx4 l1 = *(const floatx4*)&Lex[128 + r0];
#pragma unroll
      for (int r = 0; r < 4; ++r) {
        mg[base + r0 + r] = mrow[mi][r];
        lg[base + r0 + r] = l0[r] + l1[r];
      }
    }
  }
  // P dump: plain row-major [128][256B], bank-staggered LDS reads
  _Float16* Pg = Pt + (size_t)(b * NTILE + ((i * (i + 1)) >> 1) + j) * PT_ELEMS;
  const int drow = tid >> 1, dhalf = tid & 1;
#pragma unroll
  for (int k = 0; k < 8; ++k) {
    const int c = k ^ (tid & 7);
    const uintx4 v = *(const uintx4*)(As + drow * 256 + dhalf * 128 + c * 16);
    *(uintx4*)((char*)Pg + drow * 256 + dhalf * 128 + c * 16) = v;
  }
}

// ---- combine: per row, M = max m_j, alpha_j = exp(m_j - M), linv = 1/sum ----
__global__ __launch_bounds__(256) void combine(const float* __restrict__ mg,
                                               const float* __restrict__ lg,
                                               _Float16* __restrict__ ah,
                                               float* __restrict__ linv) {
  const int gid = (int)(blockIdx.x * 256 + threadIdx.x);   // 8192
  const int b = gid >> 11, row = gid & 2047, i = row >> 7;
  const size_t mb = (size_t)b * 32768 + row;               // m[b][j][row], stride 2048
  float M = -1e30f;
  for (int j = 0; j <= i; ++j) M = fmaxf(M, mg[mb + (size_t)j * 2048]);
  float L = 0.f;
  for (int j = 0; j <= i; ++j) {
    const float a = __expf(mg[mb + (size_t)j * 2048] - M);
    L += a * lg[mb + (size_t)j * 2048];
    ah[((size_t)b * 2048 + row) * 16 + j] = (_Float16)a;
  }
  linv[b * 2048 + row] = 1.0f / L;
}

// ---- PV: O = sum_j (alpha_j P_j) V_j, 128^2 tile, BK=128, f16 ----
__global__ __launch_bounds__(256, 2) void pv(const _Float16* __restrict__ Pt,
                                             const _Float16* __restrict__ VhT,
                                             const _Float16* __restrict__ ah,
                                             const float* __restrict__ linv,
                                             float* __restrict__ O) {
  extern __shared__ __align__(16) char lds[];   // As 32K (P) | Bs 32K (VhT)
  char* As = lds;
  char* Bs = lds + 32768;
  const int tid = threadIdx.x;
  const int w = tid >> 6, l = tid & 63, l15 = l & 15, hi = l >> 4;
  const int wr = (w >> 1) * 64, wc = (w & 1) * 64;

  const int b = (int)(blockIdx.x & 3), t = (int)(blockIdx.x >> 2);
  const int r_ = t >> 3;
  const int i = (r_ < 8) ? (15 - r_) : (r_ - 8);   // co-resident pair balance
  const int nc = t & 7;
  const int ns = i + 1;

  const _Float16* Pb = Pt + (size_t)(b * NTILE + ((i * (i + 1)) >> 1)) * PT_ELEMS;
  const _Float16* Vt = VhT + ((size_t)(b * D_ + nc * 128)) * T_;
  const int srow = w * 32 + (l >> 4);
  char* Adst = As + w * 8192;
  char* Bdst = Bs + w * 8192;

  floatx4 acc[4][4];
#pragma unroll
  for (int mi = 0; mi < 4; ++mi)
#pragma unroll
    for (int ni = 0; ni < 4; ++ni) acc[mi][ni] = (floatx4){0.f, 0.f, 0.f, 0.f};

  for (int s = 0; s < ns; ++s) {
    _Float16 aw[4];                              // alpha[row][j=s], early loads
#pragma unroll
    for (int mi = 0; mi < 4; ++mi)
      aw[mi] = ah[((size_t)(b * 2048 + i * 128 + wr + mi * 16 + l15)) * 16 + s];
#pragma unroll
    for (int q = 0; q < 8; ++q) {
      const int r0 = srow + q * 4;
      const int sc = ((l & 15) ^ (r0 & 15)) * 8;
      gl16(Pb + (size_t)s * PT_ELEMS + (size_t)r0 * 128 + sc, Adst + q * 1024);
      gl16(Vt + (size_t)r0 * T_ + s * 128 + sc, Bdst + q * 1024);
    }
    __syncthreads();                             // drains gl16 AND alpha loads
#pragma unroll
    for (int s32 = 0; s32 < 4; ++s32) {
      half8 af[4], bb[4];
#pragma unroll
      for (int mi = 0; mi < 4; ++mi) {
        const int row = wr + mi * 16 + l15;
        af[mi] = *(const half8*)(As + row * 256 + (((s32 * 4 + hi) ^ (row & 15)) << 4));
        af[mi] *= aw[mi];                        // flash rescale (v_pk_mul_f16)
      }
#pragma unroll
      for (int ni = 0; ni < 4; ++ni) {
        const int row = wc + ni * 16 + l15;
        bb[ni] = *(const half8*)(Bs + row * 256 + (((s32 * 4 + hi) ^ (row & 15)) << 4));
      }
#pragma unroll
      for (int mi = 0; mi < 4; ++mi)
#pragma unroll
        for (int ni = 0; ni < 4; ++ni)
          acc[mi][ni] = MFMA16(af[mi], bb[ni], acc[mi][ni]);
    }
    __syncthreads();
  }

  float* Ob = O + ((size_t)b * T_ + i * 128) * D_ + nc * 128;
#pragma unroll
  for (int mi = 0; mi < 4; ++mi)
#pragma unroll
    for (int r = 0; r < 4; ++r) {
      const int rl = wr + mi * 16 + 4 * hi + r;
      const float iv = linv[b * 2048 + i * 128 + rl];
#pragma unroll
      for (int ni = 0; ni < 4; ++ni)
        Ob[(size_t)rl * D_ + wc + ni * 16 + l15] = acc[mi][ni][r] * iv;
    }
}

// ---- fallback (ws too small — slow but correct) ----
__global__ __launch_bounds__(256) void attn_fb(const float* __restrict__ Q,
                                               const float* __restrict__ V,
                                               float* __restrict__ O) {
  __shared__ float sc[2048];
  __shared__ float red[4];
  const int b = (int)(blockIdx.x >> 11), m = (int)(blockIdx.x & 2047);
  const int tid = threadIdx.x;
  const float* Qr = Q + ((size_t)b * T_ + m) * D_;
  for (int kv = tid; kv <= m; kv += 256) {
    const float* Vr = V + ((size_t)b * T_ + kv) * D_;
    float s = 0.f;
    for (int d = 0; d < D_; d += 4) {
      floatx4 q4 = *(const floatx4*)(Qr + d), v4 = *(const floatx4*)(Vr + d);
      s += q4[0] * v4[0] + q4[1] * v4[1] + q4[2] * v4[2] + q4[3] * v4[3];
    }
    sc[kv] = s;
  }
  __syncthreads();
  float mx = -1e30f;
  for (int kv = tid; kv <= m; kv += 256) mx = fmaxf(mx, sc[kv]);
#pragma unroll
  for (int off = 1; off < 64; off <<= 1) mx = fmaxf(mx, __shfl_xor(mx, off));
  if ((tid & 63) == 0) red[tid >> 6] = mx;
  __syncthreads();
  mx = fmaxf(fmaxf(red[0], red[1]), fmaxf(red[2], red[3]));
  __syncthreads();
  float sum = 0.f;
  for (int kv = tid; kv <= m; kv += 256) { float p = __expf(sc[kv] - mx); sc[kv] = p; sum += p; }
#pragma unroll
  for (int off = 1; off < 64; off <<= 1) sum += __shfl_xor(sum, off);
  __syncthreads();
  if ((tid & 63) == 0) red[tid >> 6] = sum;
  __syncthreads();
  const float inv = 1.0f / (red[0] + red[1] + red[2] + red[3]);
  float* Or = O + ((size_t)b * T_ + m) * D_;
  const int d = tid * 4;
  floatx4 o = {0.f, 0.f, 0.f, 0.f};
  for (int kv = 0; kv <= m; ++kv) {
    const float p = sc[kv];
    const floatx4 v4 = *(const floatx4*)(V + ((size_t)b * T_ + kv) * D_ + d);
    o[0] += p * v4[0]; o[1] += p * v4[1]; o[2] += p * v4[2]; o[3] += p * v4[3];
  }
  o[0] *= inv; o[1] *= inv; o[2] *= inv; o[3] *= inv;
  *(floatx4*)(Or + d) = o;
}

extern "C" void kernel_launch(void* const* d_in, const int* in_sizes, int n_in,
                              void* d_out, int out_size, void* d_ws, size_t ws_size,
                              hipStream_t stream) {
  const float* q = (const float*)d_in[0];
  const float* v = (const float*)d_in[1];
  float* out = (float*)d_out;

  const size_t OFF_VH = 16777216;                       // Qh at 0 (reused as VhT)
  const size_t OFF_P  = 33554432;
  const size_t OFF_M  = OFF_P + (size_t)NB * NTILE * PT_ELEMS * 2;  // 51,380,224
  const size_t OFF_LT = OFF_M + 524288;
  const size_t OFF_AH = OFF_LT + 524288;
  const size_t OFF_LI = OFF_AH + 262144;
  const size_t NEED   = OFF_LI + 32768;                 // ~52.7 MB (< proven 67.2)

  if (ws_size >= NEED) {
    _Float16* qh = (_Float16*)d_ws;                     // later VhT
    _Float16* vh = (_Float16*)((char*)d_ws + OFF_VH);
    _Float16* pt = (_Float16*)((char*)d_ws + OFF_P);
    float* mg = (float*)((char*)d_ws + OFF_M);
    float* lg = (float*)((char*)d_ws + OFF_LT);
    _Float16* ah = (_Float16*)((char*)d_ws + OFF_AH);
    float* li = (float*)((char*)d_ws + OFF_LI);
    hipFuncSetAttribute((const void*)sgemm, hipFuncAttributeMaxDynamicSharedMemorySize, 65536);
    hipFuncSetAttribute((const void*)pv, hipFuncAttributeMaxDynamicSharedMemorySize, 65536);
    cast_h<<<dim3(4096), dim3(256), 0, stream>>>(q, qh);
    cast_h<<<dim3(4096), dim3(256), 0, stream>>>(v, vh);
    sgemm<<<dim3(NB * NTILE), dim3(256), 65536, stream>>>(qh, vh, pt, mg, lg);
    combine<<<dim3(32), dim3(256), 0, stream>>>(mg, lg, ah, li);
    build_vt<<<dim3(2048), dim3(256), 0, stream>>>(v, qh);   // Qh dead -> VhT
    pv<<<dim3(512), dim3(256), 65536, stream>>>(pt, qh, ah, li, out);
  } else {
    attn_fb<<<dim3(NB * T_), dim3(256), 0, stream>>>(q, v, out);
  }
}